// Round 5
// baseline (190.177 us; speedup 1.0000x reference)
//
#include <hip/hip_runtime.h>
#include <stdint.h>

#define B_ 2
#define S_ 2048
#define D_ 1024
#define H_ 16
#define C_ 64
#define M_ (B_*S_)     // 4096 tokens
#define N1_ (3*D_)     // 3072 qkv cols

typedef float f32x4 __attribute__((ext_vector_type(4)));
typedef float f32x16 __attribute__((ext_vector_type(16)));
typedef __bf16 bf16x8 __attribute__((ext_vector_type(8)));

#define QSCALE 0.18033688f   /* 1/sqrt(64) * log2(e), folded into Q */

// compiler-generated bf16 convert (fuses pairs into v_cvt_pk_bf16_f32)
static __device__ __forceinline__ unsigned short f2bf(float f) {
  __bf16 h = (__bf16)f;
  return __builtin_bit_cast(unsigned short, h);
}
static __device__ __forceinline__ unsigned pk2(float lo, float hi) {
  return (unsigned)f2bf(lo) | ((unsigned)f2bf(hi) << 16);
}

static __device__ __forceinline__ f32x4 mfma_bf16(uint4 a, uint4 b, f32x4 c) {
  return __builtin_amdgcn_mfma_f32_16x16x32_bf16(
      __builtin_bit_cast(bf16x8, a), __builtin_bit_cast(bf16x8, b), c, 0, 0, 0);
}
static __device__ __forceinline__ f32x16 mfma32(uint4 a, uint4 b, f32x16 c) {
  return __builtin_amdgcn_mfma_f32_32x32x16_bf16(
      __builtin_bit_cast(bf16x8, a), __builtin_bit_cast(bf16x8, b), c, 0, 0, 0);
}

// cross-half combine via shfl (known-correct HIP semantics on wave64)
static __device__ __forceinline__ float xmax32(float x) {
  return fmaxf(x, __shfl_xor(x, 32));
}
static __device__ __forceinline__ float xsum32(float x) {
  return x + __shfl_xor(x, 32);
}

// async global->LDS, 16B per lane; lds dest is wave-uniform base + lane*16
static __device__ __forceinline__ void gload16(const void* g, void* l) {
  __builtin_amdgcn_global_load_lds(
      (const __attribute__((address_space(1))) unsigned int*)g,
      (__attribute__((address_space(3))) unsigned int*)l, 16, 0, 0);
}

// ---------------- cast fp32 -> bf16 (8 elems/thread) ----------------
__global__ __launch_bounds__(256) void cast_f32_bf16(
    const float* __restrict__ src, unsigned short* __restrict__ dst, int n8) {
  int i = blockIdx.x * 256 + threadIdx.x;
  if (i >= n8) return;
  const float4* s4 = (const float4*)src;
  float4 a = s4[2*i], b = s4[2*i+1];
  uint4 o;
  o.x = pk2(a.x, a.y);
  o.y = pk2(a.z, a.w);
  o.z = pk2(b.x, b.y);
  o.w = pk2(b.z, b.w);
  ((uint4*)dst)[i] = o;
}

// ---------------- GEMM: C[m][n] = sum_k A[m][k]*B[n][k] + bias[n] ----
// global_load_lds staging (m97 pattern): linear LDS dest, pre-swizzled source.
// MODE 0: Cf fp32.  MODE 1: scatter to Qg/Kg [b][h][s][64] (Q pre-scaled) and
//                   Vtg [b][h][d][s] (transposed, ushort4-packed along s).
template<int MODE>
__global__ __launch_bounds__(256) void gemm_bt(
    const unsigned short* __restrict__ A,
    const unsigned short* __restrict__ Bm,
    const float* __restrict__ bias,
    float* __restrict__ Cf,
    unsigned short* __restrict__ Qg,
    unsigned short* __restrict__ Kg,
    unsigned short* __restrict__ Vtg,
    int Ndim, int Kdim)
{
  __shared__ __attribute__((aligned(16))) unsigned short As[128*32];
  __shared__ __attribute__((aligned(16))) unsigned short Bs[128*32];
  const int tid = threadIdx.x;
  const int l = tid & 63, wid = tid >> 6;
  const int g = l >> 4, lr = l & 15;
  const int m0 = blockIdx.y * 128, n0 = blockIdx.x * 128;
  const int wr = (wid >> 1) * 64, wc = (wid & 1) * 64;

  f32x4 acc[4][4] = {};

  // staging decomposition: wave wid owns rows [wid*32, wid*32+32) of As/Bs.
  // inst i in {0,1}: rows wid*32+i*16 .. +16; lane covers row (l>>2), chunk pos l&3.
  // stored logical chunk c = pos ^ (row&3)  -> source address pre-swizzled.
  const int lane4 = l >> 2;            // row within 16-row group
  const int p4 = l & 3;                // chunk position
  const int cA = p4 ^ (lane4 & 3);     // logical chunk (same for i=0,1)
  const int rA = wid*32 + lane4;
  const unsigned short* Agl = A + (size_t)(m0 + rA) * Kdim + cA*8;
  const unsigned short* Bgl = Bm + (size_t)(n0 + rA) * Kdim + cA*8;
  unsigned short* Al0 = &As[(wid*32)*32];
  unsigned short* Al1 = &As[(wid*32+16)*32];
  unsigned short* Bl0 = &Bs[(wid*32)*32];
  unsigned short* Bl1 = &Bs[(wid*32+16)*32];
  const size_t rowstep = (size_t)16 * Kdim;

  for (int k0 = 0; k0 < Kdim; k0 += 32) {
    __syncthreads();                       // readers done with LDS
    gload16(Agl + k0,           Al0);
    gload16(Agl + k0 + rowstep, Al1);
    gload16(Bgl + k0,           Bl0);
    gload16(Bgl + k0 + rowstep, Bl1);
    __syncthreads();                       // vmcnt(0) drain -> tile visible
    uint4 af[4], bf[4];
#pragma unroll
    for (int mi = 0; mi < 4; ++mi)
      af[mi] = *(const uint4*)&As[(wr + mi*16 + lr)*32 + ((g ^ (lr & 3))*8)];
#pragma unroll
    for (int ni = 0; ni < 4; ++ni)
      bf[ni] = *(const uint4*)&Bs[(wc + ni*16 + lr)*32 + ((g ^ (lr & 3))*8)];
#pragma unroll
    for (int mi = 0; mi < 4; ++mi)
#pragma unroll
      for (int ni = 0; ni < 4; ++ni)
        acc[mi][ni] = mfma_bf16(af[mi], bf[ni], acc[mi][ni]);
  }

#pragma unroll
  for (int mi = 0; mi < 4; ++mi)
#pragma unroll
    for (int ni = 0; ni < 4; ++ni) {
      if (MODE == 0) {
#pragma unroll
        for (int r = 0; r < 4; ++r) {
          const int row = m0 + wr + mi*16 + g*4 + r;
          const int col = n0 + wc + ni*16 + lr;
          Cf[(size_t)row * Ndim + col] = acc[mi][ni][r] + bias[col];
        }
      } else {
        const int colbase = n0 + wc + ni*16;         // multiple of 16
        const int h     = colbase / 192;             // uniform over the 16 lanes
        const int rem   = colbase % 192;
        const int which = rem >> 6;                  // 0=Q 1=K 2=V, uniform
        const int c     = (rem & 63) + lr;
        const float bv  = bias[colbase + lr];
        const int row0  = m0 + wr + mi*16 + g*4;     // 4 consecutive rows
        const int b     = row0 >> 11, s0 = row0 & 2047;
        if (which == 2) {
          ushort4 pk;
          pk.x = f2bf(acc[mi][ni][0] + bv);
          pk.y = f2bf(acc[mi][ni][1] + bv);
          pk.z = f2bf(acc[mi][ni][2] + bv);
          pk.w = f2bf(acc[mi][ni][3] + bv);
          *(ushort4*)(Vtg + ((size_t)(b*H_ + h)*C_ + c)*S_ + s0) = pk;
        } else {
          unsigned short* dst = (which == 0) ? Qg : Kg;
          const float scl = (which == 0) ? QSCALE : 1.0f;
#pragma unroll
          for (int r = 0; r < 4; ++r) {
            const float v = (acc[mi][ni][r] + bv) * scl;
            dst[((size_t)(b*H_ + h)*S_ + (s0 + r))*C_ + c] = f2bf(v);
          }
        }
      }
    }
}

// ---------------- causal flash attention, 32x32 swapped-operand -------
// grid: (bh=32, qtile=32), 128 threads = 2 waves x 32 q-rows = 64 rows/block.
// Q pre-scaled by QSCALE; Vt is [b][h][d][s]. Defer-max THR=8 (T13).
#define PS_ 72   /* Pw row stride in elements; 144B = multiple of 16 */
__global__ __launch_bounds__(128) void attn_fwd(
    const unsigned short* __restrict__ Qg,
    const unsigned short* __restrict__ Kg,
    const unsigned short* __restrict__ Vt,
    unsigned short* __restrict__ ctx)
{
  __shared__ __attribute__((aligned(16))) unsigned short sm[8192]; // K[64][64]+V[64][64], swizzled
  __shared__ __attribute__((aligned(16))) unsigned short Ps[2][32*PS_];
  unsigned short* Ks = sm;
  unsigned short* Vs = sm + 4096;

  const int tid = threadIdx.x, l = tid & 63, w = tid >> 6;
  const int ql = l & 31, hi = l >> 5;
  const int bh = blockIdx.x;
  const int tile = 31 - (int)blockIdx.y;        // heavy tiles dispatched first
  const int q0 = tile * 64;
  const int qw0 = q0 + w * 32;
  const int qg = qw0 + ql;
  const size_t baseK = (size_t)bh * S_ * C_;
  const size_t baseV = (size_t)bh * C_ * S_;

  // Q fragments: B-operand, 4 k-chunks of 16 (C=64)
  uint4 qreg[4];
  {
    const unsigned short* qp = Qg + baseK + (size_t)qg * C_ + hi * 8;
#pragma unroll
    for (int kc = 0; kc < 4; ++kc) qreg[kc] = *(const uint4*)(qp + 16*kc);
  }

  f32x16 acc0 = {}, acc1 = {};
  float mrun = -1e30f, lsum = 0.f;

  // staging: thread t covers row srow=t>>1 of K and V, chunks shalf*4..+3
  const int srow = tid >> 1, shalf = tid & 1;
  const unsigned short* Kgp = Kg + baseK + (size_t)srow * C_ + shalf*32;
  const unsigned short* Vgp = Vt + baseV + (size_t)srow * S_ + shalf*32;
  int off[4];
#pragma unroll
  for (int j = 0; j < 4; ++j)
    off[j] = srow*64 + (((shalf*4 + j) ^ (srow & 7))*8);
  const int kv_end = q0 + 64;

  uint4 kp[4], vp[4];
#pragma unroll
  for (int j = 0; j < 4; ++j) {
    kp[j] = *(const uint4*)(Kgp + j*8);
    vp[j] = *(const uint4*)(Vgp + j*8);
  }

  for (int kv0 = 0; kv0 < kv_end; kv0 += 64) {
    __syncthreads();                       // all waves done reading previous tile
#pragma unroll
    for (int j = 0; j < 4; ++j) {
      *(uint4*)&Ks[off[j]] = kp[j];
      *(uint4*)&Vs[off[j]] = vp[j];
    }
    __syncthreads();                       // tile visible
    if (kv0 + 64 < kv_end) {               // prefetch next tile (in flight during compute)
#pragma unroll
      for (int j = 0; j < 4; ++j) {
        kp[j] = *(const uint4*)(Kgp + (size_t)(kv0+64)*C_ + j*8);
        vp[j] = *(const uint4*)(Vgp + (kv0+64) + j*8);
      }
    }
    if (kv0 > qw0 + 31) continue;          // fully masked for this wave (uniform)

    // ---- QK^T: St[key][q], two 32-key blocks ----
    f32x16 st0 = {}, st1 = {};
    __builtin_amdgcn_s_setprio(1);
#pragma unroll
    for (int kc = 0; kc < 4; ++kc) {
      const int pc = (hi + 2*kc);
      uint4 k0 = *(const uint4*)&Ks[(ql)*64      + ((pc ^ (ql & 7))*8)];
      uint4 k1 = *(const uint4*)&Ks[(32+ql)*64   + ((pc ^ (ql & 7))*8)];
      st0 = mfma32(k0, qreg[kc], st0);
      st1 = mfma32(k1, qreg[kc], st1);
    }
    __builtin_amdgcn_s_setprio(0);

    // ---- mask (diagonal tiles only) ----
    if (kv0 + 63 > qw0) {
#pragma unroll
      for (int r = 0; r < 16; ++r) {
        const int krow = (r & 3) + 8*(r >> 2) + 4*hi;
        if (kv0 + krow      > qg) st0[r] = -1e30f;
        if (kv0 + 32 + krow > qg) st1[r] = -1e30f;
      }
    }

    // ---- online softmax with defer-max (THR=8 in log2 domain) ----
    float mt = -1e30f;
#pragma unroll
    for (int r = 0; r < 16; ++r) { mt = fmaxf(mt, st0[r]); mt = fmaxf(mt, st1[r]); }
    mt = xmax32(mt);
    if (!__all((int)(mt - mrun <= 8.0f))) {
      const float mnew = fmaxf(mrun, mt);
      const float fr = exp2f(mrun - mnew);
      mrun = mnew;
      lsum *= fr;
#pragma unroll
      for (int r = 0; r < 16; ++r) { acc0[r] *= fr; acc1[r] *= fr; }
    }
    float psum = 0.f;
#pragma unroll
    for (int r = 0; r < 16; ++r) {
      st0[r] = exp2f(st0[r] - mrun); psum += st0[r];
      st1[r] = exp2f(st1[r] - mrun); psum += st1[r];
    }
    lsum += psum;

    // ---- P -> per-wave LDS Pw[q][key] (b64 writes), then B-fragments ----
    // regs r..r+3 (r mult of 4) -> keys 8*(r>>2)+4*hi + {0..3} (verified C-layout)
    unsigned short* Pw = Ps[w];
#pragma unroll
    for (int r = 0; r < 16; r += 4) {
      const int k0i = (r >> 2)*8 + 4*hi;
      uint2 a0, a1;
      a0.x = pk2(st0[r],   st0[r+1]);  a0.y = pk2(st0[r+2], st0[r+3]);
      a1.x = pk2(st1[r],   st1[r+1]);  a1.y = pk2(st1[r+2], st1[r+3]);
      *(uint2*)&Pw[ql*PS_ + k0i]      = a0;
      *(uint2*)&Pw[ql*PS_ + 32 + k0i] = a1;
    }
    // B-frag chunk kc needs P[key=16kc+8hi+j][q=ql]
    uint4 pb[4];
#pragma unroll
    for (int kc = 0; kc < 4; ++kc)
      pb[kc] = *(const uint4*)&Pw[ql*PS_ + kc*16 + hi*8];

    // ---- PV: accT[d][q] += Vt_frag x P_frag ----
    __builtin_amdgcn_s_setprio(1);
#pragma unroll
    for (int kc = 0; kc < 4; ++kc) {
      const int pc = (hi + 2*kc);
      uint4 v0 = *(const uint4*)&Vs[(ql)*64    + ((pc ^ (ql & 7))*8)];
      uint4 v1 = *(const uint4*)&Vs[(32+ql)*64 + ((pc ^ (ql & 7))*8)];
      acc0 = mfma32(v0, pb[kc], acc0);
      acc1 = mfma32(v1, pb[kc], acc1);
    }
    __builtin_amdgcn_s_setprio(0);
  }

  // ---- epilogue: normalize, LDS transpose, coalesced store ----
  __syncthreads();                          // everyone done with K/V tiles
  const float inv = 1.0f / xsum32(lsum);
  unsigned short* E = sm + w * 2048;        // per-wave 32q x 64d region
#pragma unroll
  for (int r = 0; r < 16; ++r) {
    const int d0 = (r & 3) + 8*(r >> 2) + 4*hi;
    E[ql*64 + ( d0        ^ (8*(ql & 7)))] = f2bf(acc0[r] * inv);
    E[ql*64 + ((32 + d0)  ^ (8*(ql & 7)))] = f2bf(acc1[r] * inv);
  }
  // read back rows, vector-store to ctx [token][1024]
  const int q1 = l >> 1, half = l & 1;
  const unsigned short* Er = E + q1*64;
  const int b = bh >> 4, h = bh & 15;
  unsigned short* outp = ctx + ((size_t)(b*S_ + q0 + w*32 + q1))*D_ + h*C_;
#pragma unroll
  for (int j = 0; j < 4; ++j) {
    const int clog = half*4 + j;
    const int cx = clog ^ (q1 & 7);
    uint4 val = *(const uint4*)&Er[cx*8];
    *(uint4*)(outp + clog*8) = val;
  }
}

// ---------------- launch ---------------------------------------------
extern "C" void kernel_launch(void* const* d_in, const int* in_sizes, int n_in,
                              void* d_out, int out_size, void* d_ws, size_t ws_size,
                              hipStream_t stream) {
  const float* x    = (const float*)d_in[0];
  const float* Wqkv = (const float*)d_in[1];
  const float* bqkv = (const float*)d_in[2];
  const float* Wout = (const float*)d_in[3];
  const float* bout = (const float*)d_in[4];
  float* out = (float*)d_out;

  unsigned short* ws = (unsigned short*)d_ws;
  unsigned short* xb    = ws;
  unsigned short* wqkvb = xb    + (size_t)M_ * D_;
  unsigned short* woutb = wqkvb + (size_t)N1_ * D_;
  unsigned short* Qb    = woutb + (size_t)D_ * D_;
  unsigned short* Kb    = Qb    + (size_t)B_*H_*S_*C_;
  unsigned short* Vtb   = Kb    + (size_t)B_*H_*S_*C_;
  unsigned short* ctxb  = Vtb   + (size_t)B_*H_*S_*C_;

  {
    int n8 = M_*D_/8;
    cast_f32_bf16<<<dim3((n8+255)/256), dim3(256), 0, stream>>>(x, xb, n8);
  }
  {
    int n8 = N1_*D_/8;
    cast_f32_bf16<<<dim3((n8+255)/256), dim3(256), 0, stream>>>(Wqkv, wqkvb, n8);
  }
  {
    int n8 = D_*D_/8;
    cast_f32_bf16<<<dim3((n8+255)/256), dim3(256), 0, stream>>>(Wout, woutb, n8);
  }

  gemm_bt<1><<<dim3(N1_/128, M_/128), dim3(256), 0, stream>>>(
      xb, wqkvb, bqkv, nullptr, Qb, Kb, Vtb, N1_, D_);

  attn_fwd<<<dim3(32, 32), dim3(128), 0, stream>>>(Qb, Kb, Vtb, ctxb);

  gemm_bt<0><<<dim3(D_/128, M_/128), dim3(256), 0, stream>>>(
      ctxb, woutb, bout, out, nullptr, nullptr, nullptr, D_, D_);
}

// Round 6
// 180.500 us; speedup vs baseline: 1.0536x; 1.0536x over previous
//
#include <hip/hip_runtime.h>
#include <stdint.h>

#define B_ 2
#define S_ 2048
#define D_ 1024
#define H_ 16
#define C_ 64
#define M_ (B_*S_)     // 4096 tokens
#define N1_ (3*D_)     // 3072 qkv cols

typedef float f32x4 __attribute__((ext_vector_type(4)));
typedef float f32x16 __attribute__((ext_vector_type(16)));
typedef __bf16 bf16x8 __attribute__((ext_vector_type(8)));

#define QSCALE 0.18033688f   /* 1/sqrt(64) * log2(e), folded into Q */

// compiler-generated bf16 convert (fuses pairs into v_cvt_pk_bf16_f32)
static __device__ __forceinline__ unsigned short f2bf(float f) {
  __bf16 h = (__bf16)f;
  return __builtin_bit_cast(unsigned short, h);
}
static __device__ __forceinline__ unsigned pk2(float lo, float hi) {
  return (unsigned)f2bf(lo) | ((unsigned)f2bf(hi) << 16);
}

static __device__ __forceinline__ f32x4 mfma_bf16(uint4 a, uint4 b, f32x4 c) {
  return __builtin_amdgcn_mfma_f32_16x16x32_bf16(
      __builtin_bit_cast(bf16x8, a), __builtin_bit_cast(bf16x8, b), c, 0, 0, 0);
}
static __device__ __forceinline__ f32x16 mfma32(uint4 a, uint4 b, f32x16 c) {
  return __builtin_amdgcn_mfma_f32_32x32x16_bf16(
      __builtin_bit_cast(bf16x8, a), __builtin_bit_cast(bf16x8, b), c, 0, 0, 0);
}

// cross-half combine via shfl (known-correct HIP semantics on wave64)
static __device__ __forceinline__ float xmax32(float x) {
  return fmaxf(x, __shfl_xor(x, 32));
}
static __device__ __forceinline__ float xsum32(float x) {
  return x + __shfl_xor(x, 32);
}

// async global->LDS, 16B per lane; lds dest is wave-uniform base + lane*16
static __device__ __forceinline__ void gload16(const void* g, void* l) {
  __builtin_amdgcn_global_load_lds(
      (const __attribute__((address_space(1))) unsigned int*)g,
      (__attribute__((address_space(3))) unsigned int*)l, 16, 0, 0);
}

// ---------------- cast fp32 -> bf16 (8 elems/thread) ----------------
__global__ __launch_bounds__(256) void cast_f32_bf16(
    const float* __restrict__ src, unsigned short* __restrict__ dst, int n8) {
  int i = blockIdx.x * 256 + threadIdx.x;
  if (i >= n8) return;
  const float4* s4 = (const float4*)src;
  float4 a = s4[2*i], b = s4[2*i+1];
  uint4 o;
  o.x = pk2(a.x, a.y);
  o.y = pk2(a.z, a.w);
  o.z = pk2(b.x, b.y);
  o.w = pk2(b.z, b.w);
  ((uint4*)dst)[i] = o;
}

// ---------------- GEMM: C[m][n] = sum_k A[m][k]*B[n][k] + bias[n] ----
// global_load_lds staging (m97 pattern): linear LDS dest, pre-swizzled source.
// MODE 0: Cf fp32.  MODE 1: scatter to Qg/Kg [b][h][s][64] (Q pre-scaled) and
//                   Vtg [b][h][d][s] (transposed, ushort4-packed along s).
template<int MODE>
__global__ __launch_bounds__(256) void gemm_bt(
    const unsigned short* __restrict__ A,
    const unsigned short* __restrict__ Bm,
    const float* __restrict__ bias,
    float* __restrict__ Cf,
    unsigned short* __restrict__ Qg,
    unsigned short* __restrict__ Kg,
    unsigned short* __restrict__ Vtg,
    int Ndim, int Kdim)
{
  __shared__ __attribute__((aligned(16))) unsigned short As[128*32];
  __shared__ __attribute__((aligned(16))) unsigned short Bs[128*32];
  const int tid = threadIdx.x;
  const int l = tid & 63, wid = tid >> 6;
  const int g = l >> 4, lr = l & 15;
  const int m0 = blockIdx.y * 128, n0 = blockIdx.x * 128;
  const int wr = (wid >> 1) * 64, wc = (wid & 1) * 64;

  f32x4 acc[4][4] = {};

  const int lane4 = l >> 2;            // row within 16-row group
  const int p4 = l & 3;                // chunk position
  const int cA = p4 ^ (lane4 & 3);     // logical chunk (same for i=0,1)
  const int rA = wid*32 + lane4;
  const unsigned short* Agl = A + (size_t)(m0 + rA) * Kdim + cA*8;
  const unsigned short* Bgl = Bm + (size_t)(n0 + rA) * Kdim + cA*8;
  unsigned short* Al0 = &As[(wid*32)*32];
  unsigned short* Al1 = &As[(wid*32+16)*32];
  unsigned short* Bl0 = &Bs[(wid*32)*32];
  unsigned short* Bl1 = &Bs[(wid*32+16)*32];
  const size_t rowstep = (size_t)16 * Kdim;

  for (int k0 = 0; k0 < Kdim; k0 += 32) {
    __syncthreads();                       // readers done with LDS
    gload16(Agl + k0,           Al0);
    gload16(Agl + k0 + rowstep, Al1);
    gload16(Bgl + k0,           Bl0);
    gload16(Bgl + k0 + rowstep, Bl1);
    __syncthreads();                       // vmcnt(0) drain -> tile visible
    uint4 af[4], bf[4];
#pragma unroll
    for (int mi = 0; mi < 4; ++mi)
      af[mi] = *(const uint4*)&As[(wr + mi*16 + lr)*32 + ((g ^ (lr & 3))*8)];
#pragma unroll
    for (int ni = 0; ni < 4; ++ni)
      bf[ni] = *(const uint4*)&Bs[(wc + ni*16 + lr)*32 + ((g ^ (lr & 3))*8)];
#pragma unroll
    for (int mi = 0; mi < 4; ++mi)
#pragma unroll
      for (int ni = 0; ni < 4; ++ni)
        acc[mi][ni] = mfma_bf16(af[mi], bf[ni], acc[mi][ni]);
  }

#pragma unroll
  for (int mi = 0; mi < 4; ++mi)
#pragma unroll
    for (int ni = 0; ni < 4; ++ni) {
      if (MODE == 0) {
#pragma unroll
        for (int r = 0; r < 4; ++r) {
          const int row = m0 + wr + mi*16 + g*4 + r;
          const int col = n0 + wc + ni*16 + lr;
          Cf[(size_t)row * Ndim + col] = acc[mi][ni][r] + bias[col];
        }
      } else {
        const int colbase = n0 + wc + ni*16;         // multiple of 16
        const int h     = colbase / 192;             // uniform over the 16 lanes
        const int rem   = colbase % 192;
        const int which = rem >> 6;                  // 0=Q 1=K 2=V, uniform
        const int c     = (rem & 63) + lr;
        const float bv  = bias[colbase + lr];
        const int row0  = m0 + wr + mi*16 + g*4;     // 4 consecutive rows
        const int b     = row0 >> 11, s0 = row0 & 2047;
        if (which == 2) {
          ushort4 pk;
          pk.x = f2bf(acc[mi][ni][0] + bv);
          pk.y = f2bf(acc[mi][ni][1] + bv);
          pk.z = f2bf(acc[mi][ni][2] + bv);
          pk.w = f2bf(acc[mi][ni][3] + bv);
          *(ushort4*)(Vtg + ((size_t)(b*H_ + h)*C_ + c)*S_ + s0) = pk;
        } else {
          unsigned short* dst = (which == 0) ? Qg : Kg;
          const float scl = (which == 0) ? QSCALE : 1.0f;
#pragma unroll
          for (int r = 0; r < 4; ++r) {
            const float v = (acc[mi][ni][r] + bv) * scl;
            dst[((size_t)(b*H_ + h)*S_ + (s0 + r))*C_ + c] = f2bf(v);
          }
        }
      }
    }
}

// ---------------- causal flash attention, 32x32 swapped-operand -------
// grid: (bh=32, ygrp=16), 256 threads = 4 waves x 32 q-rows = 128 rows.
// KVBLK=128 (4 x 32-key sub-blocks per barrier pair). Q pre-scaled; Vt [b][h][d][s].
// Complementary tile permutation: co-resident blocks y and y+8 sum to 17 kv128-iters.
#define PS_ 36   /* Pw row stride in elems: 72B, 8B-aligned, 2-way-max banks */
__global__ __launch_bounds__(256) void attn_fwd(
    const unsigned short* __restrict__ Qg,
    const unsigned short* __restrict__ Kg,
    const unsigned short* __restrict__ Vt,
    unsigned short* __restrict__ ctx)
{
  __shared__ __attribute__((aligned(16))) unsigned short Ks[128*64]; // [key][c] swizzled
  __shared__ __attribute__((aligned(16))) unsigned short Vs[64*128]; // [d][key] swizzled
  __shared__ __attribute__((aligned(16))) unsigned short Ps[4][32*PS_];

  const int tid = threadIdx.x, l = tid & 63, w = tid >> 6;
  const int ql = l & 31, hi = l >> 5;
  const int bh = blockIdx.x;
  const int y = (int)blockIdx.y;
  const int tile = (y < 8) ? (15 - y) : (y - 8);   // pairs (15,0),(14,1),... per CU
  const int q0 = tile * 128;
  const int qw0 = q0 + w * 32;
  const int qg = qw0 + ql;
  const size_t baseK = (size_t)bh * S_ * C_;
  const size_t baseV = (size_t)bh * C_ * S_;

  // Q fragments: B-operand, 4 k-chunks of 16 (C=64)
  uint4 qreg[4];
  {
    const unsigned short* qp = Qg + baseK + (size_t)qg * C_ + hi * 8;
#pragma unroll
    for (int kc = 0; kc < 4; ++kc) qreg[kc] = *(const uint4*)(qp + 16*kc);
  }

  f32x16 acc0 = {}, acc1 = {};
  float mrun = -1e30f, lsum = 0.f;

  // K staging: thread t -> K row t>>1 (0..127), half t&1 (4x16B chunks)
  const int krow = tid >> 1, khalf = tid & 1;
  const unsigned short* Kgp = Kg + baseK + (size_t)krow * C_ + khalf*32;
  int koff[4];
#pragma unroll
  for (int j = 0; j < 4; ++j) {
    const int ck = khalf*4 + j;
    koff[j] = krow*64 + ((ck ^ (krow & 7))*8);
  }
  // V staging: thread t -> V d-row t>>2 (0..63), quarter t&3 (4x16B chunks)
  const int vrow = tid >> 2, vq = tid & 3;
  const unsigned short* Vgp = Vt + baseV + (size_t)vrow * S_ + vq*32;
  int voff[4];
#pragma unroll
  for (int j = 0; j < 4; ++j) {
    const int ck = vq*4 + j;                        // kv chunk 0..15
    voff[j] = vrow*128 + (((ck & 8) | ((ck & 7) ^ (vrow & 7)))*8);
  }
  const int kv_end = q0 + 128;

  uint4 kp[4], vp[4];
#pragma unroll
  for (int j = 0; j < 4; ++j) {
    kp[j] = *(const uint4*)(Kgp + j*8);
    vp[j] = *(const uint4*)(Vgp + j*8);
  }

  for (int kv0 = 0; kv0 < kv_end; kv0 += 128) {
    __syncthreads();                       // all waves done reading previous tile
#pragma unroll
    for (int j = 0; j < 4; ++j) {
      *(uint4*)&Ks[koff[j]] = kp[j];
      *(uint4*)&Vs[voff[j]] = vp[j];
    }
    __syncthreads();                       // tile visible
    if (kv0 + 128 < kv_end) {              // prefetch next tile (in flight over compute)
#pragma unroll
      for (int j = 0; j < 4; ++j) {
        kp[j] = *(const uint4*)(Kgp + (size_t)(kv0+128)*C_ + j*8);
        vp[j] = *(const uint4*)(Vgp + (kv0+128) + j*8);
      }
    }

    unsigned short* Pw = Ps[w];
#pragma unroll
    for (int kb = 0; kb < 4; ++kb) {
      const int kvb = kv0 + kb*32;
      if (kvb > qw0 + 31) break;           // causal frontier (wave-uniform)

      // ---- QK^T: st[key 32][q 32] ----
      f32x16 st = {};
      __builtin_amdgcn_s_setprio(1);
#pragma unroll
      for (int kc = 0; kc < 4; ++kc) {
        const int pc = hi + 2*kc;
        uint4 kf = *(const uint4*)&Ks[(kb*32 + ql)*64 + ((pc ^ (ql & 7))*8)];
        st = mfma32(kf, qreg[kc], st);
      }
      __builtin_amdgcn_s_setprio(0);

      // ---- mask (diagonal sub-blocks only) ----
      if (kvb + 31 > qw0) {
#pragma unroll
        for (int r = 0; r < 16; ++r) {
          const int key = kvb + (r & 3) + 8*(r >> 2) + 4*hi;
          if (key > qg) st[r] = -1e30f;
        }
      }

      // ---- online softmax with defer-max (THR=8, log2 domain) ----
      float mt = -1e30f;
#pragma unroll
      for (int r = 0; r < 16; ++r) mt = fmaxf(mt, st[r]);
      mt = xmax32(mt);
      if (!__all((int)(mt - mrun <= 8.0f))) {
        const float mnew = fmaxf(mrun, mt);
        const float fr = exp2f(mrun - mnew);
        mrun = mnew;
        lsum *= fr;
#pragma unroll
        for (int r = 0; r < 16; ++r) { acc0[r] *= fr; acc1[r] *= fr; }
      }
      float psum = 0.f;
#pragma unroll
      for (int r = 0; r < 16; ++r) { st[r] = exp2f(st[r] - mrun); psum += st[r]; }
      lsum += psum;

      // ---- P -> per-wave LDS Pw[q][key32] (b64 writes, 2-way max) ----
#pragma unroll
      for (int r = 0; r < 16; r += 4) {
        const int k0i = (r >> 2)*8 + 4*hi;
        uint2 a;
        a.x = pk2(st[r],   st[r+1]);
        a.y = pk2(st[r+2], st[r+3]);
        *(uint2*)&Pw[ql*PS_ + k0i] = a;
      }
      // B-frags: chunk c needs P[key=16c+8hi+j][q=ql] (2x b64 each)
      uint4 pb0, pb1;
      {
        uint2 lo0 = *(const uint2*)&Pw[ql*PS_ + 8*hi];
        uint2 hi0 = *(const uint2*)&Pw[ql*PS_ + 8*hi + 4];
        uint2 lo1 = *(const uint2*)&Pw[ql*PS_ + 16 + 8*hi];
        uint2 hi1 = *(const uint2*)&Pw[ql*PS_ + 16 + 8*hi + 4];
        pb0 = (uint4){lo0.x, lo0.y, hi0.x, hi0.y};
        pb1 = (uint4){lo1.x, lo1.y, hi1.x, hi1.y};
      }

      // ---- PV: accT[d][q] += V_frag x P_frag ----
      __builtin_amdgcn_s_setprio(1);
#pragma unroll
      for (int c = 0; c < 2; ++c) {
        const int vck = kb*4 + 2*c + hi;     // kv 8-chunk index 0..15
        const uint4 pbc = (c == 0) ? pb0 : pb1;
        uint4 v0 = *(const uint4*)&Vs[(ql)*128    + (((vck & 8) | ((vck & 7) ^ (ql & 7)))*8)];
        uint4 v1 = *(const uint4*)&Vs[(32+ql)*128 + (((vck & 8) | ((vck & 7) ^ (ql & 7)))*8)];
        acc0 = mfma32(v0, pbc, acc0);
        acc1 = mfma32(v1, pbc, acc1);
      }
      __builtin_amdgcn_s_setprio(0);
    }
  }

  // ---- epilogue: normalize, LDS transpose, coalesced store ----
  __syncthreads();                          // everyone done with K/V tiles
  const float inv = 1.0f / xsum32(lsum);
  unsigned short* E = Ks + w * 2048;        // per-wave 32q x 64d region
#pragma unroll
  for (int r = 0; r < 16; ++r) {
    const int d0 = (r & 3) + 8*(r >> 2) + 4*hi;
    E[ql*64 + ( d0        ^ (8*(ql & 7)))] = f2bf(acc0[r] * inv);
    E[ql*64 + ((32 + d0)  ^ (8*(ql & 7)))] = f2bf(acc1[r] * inv);
  }
  // read back rows, vector-store to ctx [token][1024]
  const int q1 = l >> 1, half = l & 1;
  const unsigned short* Er = E + q1*64;
  const int b = bh >> 4, h = bh & 15;
  unsigned short* outp = ctx + ((size_t)(b*S_ + q0 + w*32 + q1))*D_ + h*C_;
#pragma unroll
  for (int j = 0; j < 4; ++j) {
    const int clog = half*4 + j;
    const int cx = clog ^ (q1 & 7);
    uint4 val = *(const uint4*)&Er[cx*8];
    *(uint4*)(outp + clog*8) = val;
  }
}

// ---------------- launch ---------------------------------------------
extern "C" void kernel_launch(void* const* d_in, const int* in_sizes, int n_in,
                              void* d_out, int out_size, void* d_ws, size_t ws_size,
                              hipStream_t stream) {
  const float* x    = (const float*)d_in[0];
  const float* Wqkv = (const float*)d_in[1];
  const float* bqkv = (const float*)d_in[2];
  const float* Wout = (const float*)d_in[3];
  const float* bout = (const float*)d_in[4];
  float* out = (float*)d_out;

  unsigned short* ws = (unsigned short*)d_ws;
  unsigned short* xb    = ws;
  unsigned short* wqkvb = xb    + (size_t)M_ * D_;
  unsigned short* woutb = wqkvb + (size_t)N1_ * D_;
  unsigned short* Qb    = woutb + (size_t)D_ * D_;
  unsigned short* Kb    = Qb    + (size_t)B_*H_*S_*C_;
  unsigned short* Vtb   = Kb    + (size_t)B_*H_*S_*C_;
  unsigned short* ctxb  = Vtb   + (size_t)B_*H_*S_*C_;

  {
    int n8 = M_*D_/8;
    cast_f32_bf16<<<dim3((n8+255)/256), dim3(256), 0, stream>>>(x, xb, n8);
  }
  {
    int n8 = N1_*D_/8;
    cast_f32_bf16<<<dim3((n8+255)/256), dim3(256), 0, stream>>>(Wqkv, wqkvb, n8);
  }
  {
    int n8 = D_*D_/8;
    cast_f32_bf16<<<dim3((n8+255)/256), dim3(256), 0, stream>>>(Wout, woutb, n8);
  }

  gemm_bt<1><<<dim3(N1_/128, M_/128), dim3(256), 0, stream>>>(
      xb, wqkvb, bqkv, nullptr, Qb, Kb, Vtb, N1_, D_);

  attn_fwd<<<dim3(32, 16), dim3(256), 0, stream>>>(Qb, Kb, Vtb, ctxb);

  gemm_bt<0><<<dim3(D_/128, M_/128), dim3(256), 0, stream>>>(
      ctxb, woutb, bout, out, nullptr, nullptr, nullptr, D_, D_);
}

// Round 7
// 151.492 us; speedup vs baseline: 1.2554x; 1.1915x over previous
//
#include <hip/hip_runtime.h>
#include <stdint.h>

#define B_ 2
#define S_ 2048
#define D_ 1024
#define H_ 16
#define C_ 64
#define M_ (B_*S_)     // 4096 tokens
#define N1_ (3*D_)     // 3072 qkv cols

typedef float f32x4 __attribute__((ext_vector_type(4)));
typedef float f32x16 __attribute__((ext_vector_type(16)));
typedef __bf16 bf16x8 __attribute__((ext_vector_type(8)));

#define QSCALE 0.18033688f   /* 1/sqrt(64) * log2(e), folded into Q */

// compiler-generated bf16 convert (fuses pairs into v_cvt_pk_bf16_f32)
static __device__ __forceinline__ unsigned short f2bf(float f) {
  __bf16 h = (__bf16)f;
  return __builtin_bit_cast(unsigned short, h);
}
static __device__ __forceinline__ unsigned pk2(float lo, float hi) {
  return (unsigned)f2bf(lo) | ((unsigned)f2bf(hi) << 16);
}

static __device__ __forceinline__ f32x4 mfma_bf16(uint4 a, uint4 b, f32x4 c) {
  return __builtin_amdgcn_mfma_f32_16x16x32_bf16(
      __builtin_bit_cast(bf16x8, a), __builtin_bit_cast(bf16x8, b), c, 0, 0, 0);
}
static __device__ __forceinline__ f32x16 mfma32(uint4 a, uint4 b, f32x16 c) {
  return __builtin_amdgcn_mfma_f32_32x32x16_bf16(
      __builtin_bit_cast(bf16x8, a), __builtin_bit_cast(bf16x8, b), c, 0, 0, 0);
}

// cross-half combine via shfl (known-correct HIP semantics on wave64)
static __device__ __forceinline__ float xmax32(float x) {
  return fmaxf(x, __shfl_xor(x, 32));
}
static __device__ __forceinline__ float xsum32(float x) {
  return x + __shfl_xor(x, 32);
}

// async global->LDS, 16B per lane; lds dest is wave-uniform base + lane*16
static __device__ __forceinline__ void gload16(const void* g, void* l) {
  __builtin_amdgcn_global_load_lds(
      (const __attribute__((address_space(1))) unsigned int*)g,
      (__attribute__((address_space(3))) unsigned int*)l, 16, 0, 0);
}

// ---------------- cast fp32 -> bf16 (8 elems/thread) ----------------
__global__ __launch_bounds__(256) void cast_f32_bf16(
    const float* __restrict__ src, unsigned short* __restrict__ dst, int n8) {
  int i = blockIdx.x * 256 + threadIdx.x;
  if (i >= n8) return;
  const float4* s4 = (const float4*)src;
  float4 a = s4[2*i], b = s4[2*i+1];
  uint4 o;
  o.x = pk2(a.x, a.y);
  o.y = pk2(a.z, a.w);
  o.z = pk2(b.x, b.y);
  o.w = pk2(b.z, b.w);
  ((uint4*)dst)[i] = o;
}

// ---------------- GEMM: C[m][n] = sum_k A[m][k]*B[n][k] + bias[n] ----
// global_load_lds staging (m97 pattern): linear LDS dest, pre-swizzled source.
// MODE 0: Cf fp32.  MODE 1: scatter to Qg/Kg [b][h][s][64] (Q pre-scaled) and
//                   Vtg [b][h][d][s] (transposed, ushort4-packed along s).
template<int MODE>
__global__ __launch_bounds__(256) void gemm_bt(
    const unsigned short* __restrict__ A,
    const unsigned short* __restrict__ Bm,
    const float* __restrict__ bias,
    float* __restrict__ Cf,
    unsigned short* __restrict__ Qg,
    unsigned short* __restrict__ Kg,
    unsigned short* __restrict__ Vtg,
    int Ndim, int Kdim)
{
  __shared__ __attribute__((aligned(16))) unsigned short As[128*32];
  __shared__ __attribute__((aligned(16))) unsigned short Bs[128*32];
  const int tid = threadIdx.x;
  const int l = tid & 63, wid = tid >> 6;
  const int g = l >> 4, lr = l & 15;
  const int m0 = blockIdx.y * 128, n0 = blockIdx.x * 128;
  const int wr = (wid >> 1) * 64, wc = (wid & 1) * 64;

  f32x4 acc[4][4] = {};

  const int lane4 = l >> 2;            // row within 16-row group
  const int p4 = l & 3;                // chunk position
  const int cA = p4 ^ (lane4 & 3);     // logical chunk (same for i=0,1)
  const int rA = wid*32 + lane4;
  const unsigned short* Agl = A + (size_t)(m0 + rA) * Kdim + cA*8;
  const unsigned short* Bgl = Bm + (size_t)(n0 + rA) * Kdim + cA*8;
  unsigned short* Al0 = &As[(wid*32)*32];
  unsigned short* Al1 = &As[(wid*32+16)*32];
  unsigned short* Bl0 = &Bs[(wid*32)*32];
  unsigned short* Bl1 = &Bs[(wid*32+16)*32];
  const size_t rowstep = (size_t)16 * Kdim;

  for (int k0 = 0; k0 < Kdim; k0 += 32) {
    __syncthreads();                       // readers done with LDS
    gload16(Agl + k0,           Al0);
    gload16(Agl + k0 + rowstep, Al1);
    gload16(Bgl + k0,           Bl0);
    gload16(Bgl + k0 + rowstep, Bl1);
    __syncthreads();                       // vmcnt(0) drain -> tile visible
    uint4 af[4], bf[4];
#pragma unroll
    for (int mi = 0; mi < 4; ++mi)
      af[mi] = *(const uint4*)&As[(wr + mi*16 + lr)*32 + ((g ^ (lr & 3))*8)];
#pragma unroll
    for (int ni = 0; ni < 4; ++ni)
      bf[ni] = *(const uint4*)&Bs[(wc + ni*16 + lr)*32 + ((g ^ (lr & 3))*8)];
#pragma unroll
    for (int mi = 0; mi < 4; ++mi)
#pragma unroll
      for (int ni = 0; ni < 4; ++ni)
        acc[mi][ni] = mfma_bf16(af[mi], bf[ni], acc[mi][ni]);
  }

#pragma unroll
  for (int mi = 0; mi < 4; ++mi)
#pragma unroll
    for (int ni = 0; ni < 4; ++ni) {
      if (MODE == 0) {
#pragma unroll
        for (int r = 0; r < 4; ++r) {
          const int row = m0 + wr + mi*16 + g*4 + r;
          const int col = n0 + wc + ni*16 + lr;
          Cf[(size_t)row * Ndim + col] = acc[mi][ni][r] + bias[col];
        }
      } else {
        const int colbase = n0 + wc + ni*16;         // multiple of 16
        const int h     = colbase / 192;             // uniform over the 16 lanes
        const int rem   = colbase % 192;
        const int which = rem >> 6;                  // 0=Q 1=K 2=V, uniform
        const int c     = (rem & 63) + lr;
        const float bv  = bias[colbase + lr];
        const int row0  = m0 + wr + mi*16 + g*4;     // 4 consecutive rows
        const int b     = row0 >> 11, s0 = row0 & 2047;
        if (which == 2) {
          ushort4 pk;
          pk.x = f2bf(acc[mi][ni][0] + bv);
          pk.y = f2bf(acc[mi][ni][1] + bv);
          pk.z = f2bf(acc[mi][ni][2] + bv);
          pk.w = f2bf(acc[mi][ni][3] + bv);
          *(ushort4*)(Vtg + ((size_t)(b*H_ + h)*C_ + c)*S_ + s0) = pk;
        } else {
          unsigned short* dst = (which == 0) ? Qg : Kg;
          const float scl = (which == 0) ? QSCALE : 1.0f;
#pragma unroll
          for (int r = 0; r < 4; ++r) {
            const float v = (acc[mi][ni][r] + bv) * scl;
            dst[((size_t)(b*H_ + h)*S_ + (s0 + r))*C_ + c] = f2bf(v);
          }
        }
      }
    }
}

// ---------------- causal flash attention, 32x32 swapped-operand -------
// grid: (bh=32, ygrp=16), 256 threads = 4 waves x 32 q-rows = 128 rows.
// R4 compute structure (KVBLK=64) + async global_load_lds double-buffer staging.
// Q pre-scaled by QSCALE; Vt is [b][h][d][s]. Defer-max THR=8 (T13).
#define PS_ 72   /* Pw row stride in elements; 144B = multiple of 16 */
__global__ __launch_bounds__(256) void attn_fwd(
    const unsigned short* __restrict__ Qg,
    const unsigned short* __restrict__ Kg,
    const unsigned short* __restrict__ Vt,
    unsigned short* __restrict__ ctx)
{
  // buffer bi: K tile [64 key][64 c] at [bi][0..4096), V tile [64 d][64 kv] at [bi][4096..8192)
  __shared__ __attribute__((aligned(16))) unsigned short KV[2][8192];
  __shared__ __attribute__((aligned(16))) unsigned short Ps[4][32*PS_];

  const int tid = threadIdx.x, l = tid & 63, w = tid >> 6;
  const int ql = l & 31, hi = l >> 5;
  const int bh = blockIdx.x;
  const int y = (int)blockIdx.y;
  const int tile = (y < 8) ? (15 - y) : (y - 8);   // complementary pairs per CU
  const int q0 = tile * 128;
  const int qw0 = q0 + w * 32;
  const int qg = qw0 + ql;
  const size_t baseK = (size_t)bh * S_ * C_;
  const size_t baseV = (size_t)bh * C_ * S_;

  // Q fragments: B-operand, 4 k-chunks of 16 (C=64)
  uint4 qreg[4];
  {
    const unsigned short* qp = Qg + baseK + (size_t)qg * C_ + hi * 8;
#pragma unroll
    for (int kc = 0; kc < 4; ++kc) qreg[kc] = *(const uint4*)(qp + 16*kc);
  }

  f32x16 acc0 = {}, acc1 = {};
  float mrun = -1e30f, lsum = 0.f;

  // ---- async staging geometry: wave w stages rows [w*16, w*16+16) of K and V ----
  // lane l covers row lq = l>>3 (within 8-row inst), position p = l&7;
  // stored layout = logical chunk c at position c ^ (row&7)  ->  source chunk lc = p ^ lq
  const int lq = l >> 3;
  const int lc = (l & 7) ^ lq;
  const unsigned short* kgl = Kg + baseK + (size_t)(w*16 + lq) * C_ + lc*8;
  const unsigned short* vgl = Vt + baseV + (size_t)(w*16 + lq) * S_ + lc*8;
  const int kv_end = q0 + 128;

#define STAGE(bi, kvo) do { \
    unsigned short* kb_ = &KV[bi][(w*16)*64]; \
    unsigned short* vb_ = &KV[bi][4096 + (w*16)*64]; \
    gload16(kgl + (size_t)(kvo)*C_,        kb_); \
    gload16(kgl + (size_t)(kvo)*C_ + 8*C_, kb_ + 8*64); \
    gload16(vgl + (kvo),                   vb_); \
    gload16(vgl + (kvo) + 8*(size_t)S_,    vb_ + 8*64); \
  } while (0)

  int cur = 0;
  STAGE(0, 0);
  asm volatile("s_waitcnt vmcnt(0)" ::: "memory");
  __builtin_amdgcn_s_barrier();
  __builtin_amdgcn_sched_barrier(0);

  for (int kv0 = 0; kv0 < kv_end; kv0 += 64) {
    const bool nxt = (kv0 + 64 < kv_end);
    if (nxt) STAGE(cur ^ 1, kv0 + 64);     // async, in flight over compute

    if (kv0 <= qw0 + 31) {                 // wave-uniform causal skip
      const unsigned short* Ks = &KV[cur][0];
      const unsigned short* Vs = &KV[cur][4096];

      // ---- QK^T: St[key][q], two 32-key blocks ----
      f32x16 st0 = {}, st1 = {};
      __builtin_amdgcn_s_setprio(1);
#pragma unroll
      for (int kc = 0; kc < 4; ++kc) {
        const int pc = (hi + 2*kc);
        uint4 k0 = *(const uint4*)&Ks[(ql)*64      + ((pc ^ (ql & 7))*8)];
        uint4 k1 = *(const uint4*)&Ks[(32+ql)*64   + ((pc ^ (ql & 7))*8)];
        st0 = mfma32(k0, qreg[kc], st0);
        st1 = mfma32(k1, qreg[kc], st1);
      }
      __builtin_amdgcn_s_setprio(0);

      // ---- mask (diagonal tiles only) ----
      if (kv0 + 63 > qw0) {
#pragma unroll
        for (int r = 0; r < 16; ++r) {
          const int krow = (r & 3) + 8*(r >> 2) + 4*hi;
          if (kv0 + krow      > qg) st0[r] = -1e30f;
          if (kv0 + 32 + krow > qg) st1[r] = -1e30f;
        }
      }

      // ---- online softmax with defer-max (THR=8, log2 domain) ----
      float mt = -1e30f;
#pragma unroll
      for (int r = 0; r < 16; ++r) { mt = fmaxf(mt, st0[r]); mt = fmaxf(mt, st1[r]); }
      mt = xmax32(mt);
      if (!__all((int)(mt - mrun <= 8.0f))) {
        const float mnew = fmaxf(mrun, mt);
        const float fr = exp2f(mrun - mnew);
        mrun = mnew;
        lsum *= fr;
#pragma unroll
        for (int r = 0; r < 16; ++r) { acc0[r] *= fr; acc1[r] *= fr; }
      }
      float psum = 0.f;
#pragma unroll
      for (int r = 0; r < 16; ++r) {
        st0[r] = exp2f(st0[r] - mrun); psum += st0[r];
        st1[r] = exp2f(st1[r] - mrun); psum += st1[r];
      }
      lsum += psum;

      // ---- P -> per-wave LDS Pw[q][key] (b64 writes), then B-fragments ----
      unsigned short* Pw = Ps[w];
#pragma unroll
      for (int r = 0; r < 16; r += 4) {
        const int k0i = (r >> 2)*8 + 4*hi;
        uint2 a0, a1;
        a0.x = pk2(st0[r],   st0[r+1]);  a0.y = pk2(st0[r+2], st0[r+3]);
        a1.x = pk2(st1[r],   st1[r+1]);  a1.y = pk2(st1[r+2], st1[r+3]);
        *(uint2*)&Pw[ql*PS_ + k0i]      = a0;
        *(uint2*)&Pw[ql*PS_ + 32 + k0i] = a1;
      }
      uint4 pb[4];
#pragma unroll
      for (int kc = 0; kc < 4; ++kc)
        pb[kc] = *(const uint4*)&Pw[ql*PS_ + kc*16 + hi*8];

      // ---- PV: accT[d][q] += V_frag x P_frag ----
      __builtin_amdgcn_s_setprio(1);
#pragma unroll
      for (int kc = 0; kc < 4; ++kc) {
        const int pc = (hi + 2*kc);
        uint4 v0 = *(const uint4*)&Vs[(ql)*64    + ((pc ^ (ql & 7))*8)];
        uint4 v1 = *(const uint4*)&Vs[(32+ql)*64 + ((pc ^ (ql & 7))*8)];
        acc0 = mfma32(v0, pb[kc], acc0);
        acc1 = mfma32(v1, pb[kc], acc1);
      }
      __builtin_amdgcn_s_setprio(0);
    }

    if (nxt) {
      asm volatile("s_waitcnt vmcnt(0)" ::: "memory");  // next tile landed
      __builtin_amdgcn_s_barrier();                     // all slices visible
      __builtin_amdgcn_sched_barrier(0);
    }
    cur ^= 1;
  }
#undef STAGE

  // ---- epilogue: normalize, LDS transpose, coalesced store ----
  __syncthreads();                          // everyone done with K/V tiles
  const float inv = 1.0f / xsum32(lsum);
  unsigned short* E = &KV[0][0] + w * 2048; // per-wave 32q x 64d region
#pragma unroll
  for (int r = 0; r < 16; ++r) {
    const int d0 = (r & 3) + 8*(r >> 2) + 4*hi;
    E[ql*64 + ( d0        ^ (8*(ql & 7)))] = f2bf(acc0[r] * inv);
    E[ql*64 + ((32 + d0)  ^ (8*(ql & 7)))] = f2bf(acc1[r] * inv);
  }
  __syncthreads();
  // read back rows, vector-store to ctx [token][1024]
  const int q1 = l >> 1, half = l & 1;
  const unsigned short* Er = E + q1*64;
  const int b = bh >> 4, h = bh & 15;
  unsigned short* outp = ctx + ((size_t)(b*S_ + q0 + w*32 + q1))*D_ + h*C_;
#pragma unroll
  for (int j = 0; j < 4; ++j) {
    const int clog = half*4 + j;
    const int cx = clog ^ (q1 & 7);
    uint4 val = *(const uint4*)&Er[cx*8];
    *(uint4*)(outp + clog*8) = val;
  }
}

// ---------------- launch ---------------------------------------------
extern "C" void kernel_launch(void* const* d_in, const int* in_sizes, int n_in,
                              void* d_out, int out_size, void* d_ws, size_t ws_size,
                              hipStream_t stream) {
  const float* x    = (const float*)d_in[0];
  const float* Wqkv = (const float*)d_in[1];
  const float* bqkv = (const float*)d_in[2];
  const float* Wout = (const float*)d_in[3];
  const float* bout = (const float*)d_in[4];
  float* out = (float*)d_out;

  unsigned short* ws = (unsigned short*)d_ws;
  unsigned short* xb    = ws;
  unsigned short* wqkvb = xb    + (size_t)M_ * D_;
  unsigned short* woutb = wqkvb + (size_t)N1_ * D_;
  unsigned short* Qb    = woutb + (size_t)D_ * D_;
  unsigned short* Kb    = Qb    + (size_t)B_*H_*S_*C_;
  unsigned short* Vtb   = Kb    + (size_t)B_*H_*S_*C_;
  unsigned short* ctxb  = Vtb   + (size_t)B_*H_*S_*C_;

  {
    int n8 = M_*D_/8;
    cast_f32_bf16<<<dim3((n8+255)/256), dim3(256), 0, stream>>>(x, xb, n8);
  }
  {
    int n8 = N1_*D_/8;
    cast_f32_bf16<<<dim3((n8+255)/256), dim3(256), 0, stream>>>(Wqkv, wqkvb, n8);
  }
  {
    int n8 = D_*D_/8;
    cast_f32_bf16<<<dim3((n8+255)/256), dim3(256), 0, stream>>>(Wout, woutb, n8);
  }

  gemm_bt<1><<<dim3(N1_/128, M_/128), dim3(256), 0, stream>>>(
      xb, wqkvb, bqkv, nullptr, Qb, Kb, Vtb, N1_, D_);

  attn_fwd<<<dim3(32, 16), dim3(256), 0, stream>>>(Qb, Kb, Vtb, ctxb);

  gemm_bt<0><<<dim3(D_/128, M_/128), dim3(256), 0, stream>>>(
      ctxb, woutb, bout, out, nullptr, nullptr, nullptr, D_, D_);
}

// Round 8
// 146.753 us; speedup vs baseline: 1.2959x; 1.0323x over previous
//
#include <hip/hip_runtime.h>
#include <stdint.h>

#define B_ 2
#define S_ 2048
#define D_ 1024
#define H_ 16
#define C_ 64
#define M_ (B_*S_)     // 4096 tokens
#define N1_ (3*D_)     // 3072 qkv cols

typedef float f32x4 __attribute__((ext_vector_type(4)));
typedef float f32x16 __attribute__((ext_vector_type(16)));
typedef __bf16 bf16x8 __attribute__((ext_vector_type(8)));

#define QSCALE 0.18033688f   /* 1/sqrt(64) * log2(e), folded into Q */

// compiler-generated bf16 convert (fuses pairs into v_cvt_pk_bf16_f32)
static __device__ __forceinline__ unsigned short f2bf(float f) {
  __bf16 h = (__bf16)f;
  return __builtin_bit_cast(unsigned short, h);
}
static __device__ __forceinline__ unsigned pk2(float lo, float hi) {
  return (unsigned)f2bf(lo) | ((unsigned)f2bf(hi) << 16);
}

static __device__ __forceinline__ f32x4 mfma_bf16(uint4 a, uint4 b, f32x4 c) {
  return __builtin_amdgcn_mfma_f32_16x16x32_bf16(
      __builtin_bit_cast(bf16x8, a), __builtin_bit_cast(bf16x8, b), c, 0, 0, 0);
}
static __device__ __forceinline__ f32x16 mfma32(uint4 a, uint4 b, f32x16 c) {
  return __builtin_amdgcn_mfma_f32_32x32x16_bf16(
      __builtin_bit_cast(bf16x8, a), __builtin_bit_cast(bf16x8, b), c, 0, 0, 0);
}

// cross-half combine via shfl (known-correct HIP semantics on wave64)
static __device__ __forceinline__ float xmax32(float x) {
  return fmaxf(x, __shfl_xor(x, 32));
}
static __device__ __forceinline__ float xsum32(float x) {
  return x + __shfl_xor(x, 32);
}

// async global->LDS, 16B per lane; lds dest is wave-uniform base + lane*16
static __device__ __forceinline__ void gload16(const void* g, void* l) {
  __builtin_amdgcn_global_load_lds(
      (const __attribute__((address_space(1))) unsigned int*)g,
      (__attribute__((address_space(3))) unsigned int*)l, 16, 0, 0);
}

// ---------------- fused cast fp32 -> bf16 for x, W_qkv, W_out ---------
#define N8X (M_*D_/8)
#define N8W (N1_*D_/8)
#define N8O (D_*D_/8)
__global__ __launch_bounds__(256) void cast_all(
    const float* __restrict__ x,   unsigned short* __restrict__ xb,
    const float* __restrict__ wq,  unsigned short* __restrict__ wqb,
    const float* __restrict__ wo,  unsigned short* __restrict__ wob) {
  int i = blockIdx.x * 256 + threadIdx.x;
  const float* src; unsigned short* dst; int j;
  if (i < N8X)              { src = x;  dst = xb;  j = i; }
  else if (i < N8X + N8W)   { src = wq; dst = wqb; j = i - N8X; }
  else                      { src = wo; dst = wob; j = i - N8X - N8W; }
  const float4* s4 = (const float4*)src;
  float4 a = s4[2*j], b = s4[2*j+1];
  uint4 o;
  o.x = pk2(a.x, a.y);
  o.y = pk2(a.z, a.w);
  o.z = pk2(b.x, b.y);
  o.w = pk2(b.z, b.w);
  ((uint4*)dst)[j] = o;
}

// ---------------- GEMM: C[m][n] = sum_k A[m][k]*B[n][k] + bias[n] ----
// global_load_lds staging (m97 pattern): linear LDS dest, pre-swizzled source.
// MODE 0: Cf fp32.  MODE 1: scatter to Qg/Kg [b][h][s][64] (Q pre-scaled) and
//                   Vtg [b][h][d][s] (transposed, ushort4-packed along s).
template<int MODE>
__global__ __launch_bounds__(256) void gemm_bt(
    const unsigned short* __restrict__ A,
    const unsigned short* __restrict__ Bm,
    const float* __restrict__ bias,
    float* __restrict__ Cf,
    unsigned short* __restrict__ Qg,
    unsigned short* __restrict__ Kg,
    unsigned short* __restrict__ Vtg,
    int Ndim, int Kdim)
{
  __shared__ __attribute__((aligned(16))) unsigned short As[128*32];
  __shared__ __attribute__((aligned(16))) unsigned short Bs[128*32];
  const int tid = threadIdx.x;
  const int l = tid & 63, wid = tid >> 6;
  const int g = l >> 4, lr = l & 15;
  const int m0 = blockIdx.y * 128, n0 = blockIdx.x * 128;
  const int wr = (wid >> 1) * 64, wc = (wid & 1) * 64;

  f32x4 acc[4][4] = {};

  const int lane4 = l >> 2;            // row within 16-row group
  const int p4 = l & 3;                // chunk position
  const int cA = p4 ^ (lane4 & 3);     // logical chunk (same for i=0,1)
  const int rA = wid*32 + lane4;
  const unsigned short* Agl = A + (size_t)(m0 + rA) * Kdim + cA*8;
  const unsigned short* Bgl = Bm + (size_t)(n0 + rA) * Kdim + cA*8;
  unsigned short* Al0 = &As[(wid*32)*32];
  unsigned short* Al1 = &As[(wid*32+16)*32];
  unsigned short* Bl0 = &Bs[(wid*32)*32];
  unsigned short* Bl1 = &Bs[(wid*32+16)*32];
  const size_t rowstep = (size_t)16 * Kdim;

  for (int k0 = 0; k0 < Kdim; k0 += 32) {
    __syncthreads();                       // readers done with LDS
    gload16(Agl + k0,           Al0);
    gload16(Agl + k0 + rowstep, Al1);
    gload16(Bgl + k0,           Bl0);
    gload16(Bgl + k0 + rowstep, Bl1);
    __syncthreads();                       // vmcnt(0) drain -> tile visible
    uint4 af[4], bf[4];
#pragma unroll
    for (int mi = 0; mi < 4; ++mi)
      af[mi] = *(const uint4*)&As[(wr + mi*16 + lr)*32 + ((g ^ (lr & 3))*8)];
#pragma unroll
    for (int ni = 0; ni < 4; ++ni)
      bf[ni] = *(const uint4*)&Bs[(wc + ni*16 + lr)*32 + ((g ^ (lr & 3))*8)];
#pragma unroll
    for (int mi = 0; mi < 4; ++mi)
#pragma unroll
      for (int ni = 0; ni < 4; ++ni)
        acc[mi][ni] = mfma_bf16(af[mi], bf[ni], acc[mi][ni]);
  }

#pragma unroll
  for (int mi = 0; mi < 4; ++mi)
#pragma unroll
    for (int ni = 0; ni < 4; ++ni) {
      if (MODE == 0) {
#pragma unroll
        for (int r = 0; r < 4; ++r) {
          const int row = m0 + wr + mi*16 + g*4 + r;
          const int col = n0 + wc + ni*16 + lr;
          Cf[(size_t)row * Ndim + col] = acc[mi][ni][r] + bias[col];
        }
      } else {
        const int colbase = n0 + wc + ni*16;         // multiple of 16
        const int h     = colbase / 192;             // uniform over the 16 lanes
        const int rem   = colbase % 192;
        const int which = rem >> 6;                  // 0=Q 1=K 2=V, uniform
        const int c     = (rem & 63) + lr;
        const float bv  = bias[colbase + lr];
        const int row0  = m0 + wr + mi*16 + g*4;     // 4 consecutive rows
        const int b     = row0 >> 11, s0 = row0 & 2047;
        if (which == 2) {
          ushort4 pk;
          pk.x = f2bf(acc[mi][ni][0] + bv);
          pk.y = f2bf(acc[mi][ni][1] + bv);
          pk.z = f2bf(acc[mi][ni][2] + bv);
          pk.w = f2bf(acc[mi][ni][3] + bv);
          *(ushort4*)(Vtg + ((size_t)(b*H_ + h)*C_ + c)*S_ + s0) = pk;
        } else {
          unsigned short* dst = (which == 0) ? Qg : Kg;
          const float scl = (which == 0) ? QSCALE : 1.0f;
#pragma unroll
          for (int r = 0; r < 4; ++r) {
            const float v = (acc[mi][ni][r] + bv) * scl;
            dst[((size_t)(b*H_ + h)*S_ + (s0 + r))*C_ + c] = f2bf(v);
          }
        }
      }
    }
}

// ---------------- causal flash attention, 32x32 swapped-operand -------
// grid: (bh=32, ygrp=16), 256 threads = 4 waves x 32 q-rows = 128 rows.
// NO K/V LDS staging (L1/L2-resident), NO barriers: waves fully independent.
// Q pre-scaled by QSCALE; Vt is [b][h][d][s]. Defer-max THR=8 (T13).
#define PS_ 72   /* Pw row stride in elements; 144B = multiple of 16 */
__global__ __launch_bounds__(256) void attn_fwd(
    const unsigned short* __restrict__ Qg,
    const unsigned short* __restrict__ Kg,
    const unsigned short* __restrict__ Vt,
    unsigned short* __restrict__ ctx)
{
  __shared__ __attribute__((aligned(16))) unsigned short Ps[4][32*PS_];

  const int tid = threadIdx.x, l = tid & 63, w = tid >> 6;
  const int ql = l & 31, hi = l >> 5;
  const int bh = blockIdx.x;
  const int y = (int)blockIdx.y;
  const int tile = (y < 8) ? (15 - y) : (y - 8);   // complementary pairs per CU
  const int q0 = tile * 128;
  const int qw0 = q0 + w * 32;
  const int qg = qw0 + ql;
  const size_t baseK = (size_t)bh * S_ * C_;
  const size_t baseV = (size_t)bh * C_ * S_;

  // Q fragments: B-operand, 4 k-chunks of 16 (C=64)
  uint4 qreg[4];
  {
    const unsigned short* qp = Qg + baseK + (size_t)qg * C_ + hi * 8;
#pragma unroll
    for (int kc = 0; kc < 4; ++kc) qreg[kc] = *(const uint4*)(qp + 16*kc);
  }

  f32x16 acc0 = {}, acc1 = {};
  float mrun = -1e30f, lsum = 0.f;

  // direct-from-global fragment pointers (L1/L2-served)
  const unsigned short* Kp  = Kg + baseK + (size_t)ql * C_ + hi * 8;  // K row ql
  const unsigned short* Kp2 = Kp + 32 * C_;                           // K row 32+ql
  const unsigned short* Vp  = Vt + baseV + (size_t)ql * S_ + hi * 8;  // V d-row ql
  const unsigned short* Vp2 = Vp + (size_t)32 * S_;                   // V d-row 32+ql
  unsigned short* Pw = Ps[w];

  const int myend = qw0 + 32;            // per-wave causal bound (no barriers!)
  for (int kv0 = 0; kv0 < myend; kv0 += 64) {
    const size_t ko = (size_t)kv0 * C_;

    // ---- K fragments + QK^T: St[key][q], two 32-key blocks ----
    uint4 kf0[4], kf1[4];
#pragma unroll
    for (int kc = 0; kc < 4; ++kc) {
      kf0[kc] = *(const uint4*)(Kp  + ko + kc*16);
      kf1[kc] = *(const uint4*)(Kp2 + ko + kc*16);
    }
    f32x16 st0 = {}, st1 = {};
    __builtin_amdgcn_s_setprio(1);
#pragma unroll
    for (int kc = 0; kc < 4; ++kc) {
      st0 = mfma32(kf0[kc], qreg[kc], st0);
      st1 = mfma32(kf1[kc], qreg[kc], st1);
    }
    __builtin_amdgcn_s_setprio(0);

    // ---- V fragments issued early: latency hides under softmax ----
    uint4 vf0[4], vf1[4];
#pragma unroll
    for (int kc = 0; kc < 4; ++kc) {
      vf0[kc] = *(const uint4*)(Vp  + kv0 + kc*16);
      vf1[kc] = *(const uint4*)(Vp2 + kv0 + kc*16);
    }

    // ---- mask (diagonal tiles only) ----
    if (kv0 + 63 > qw0) {
#pragma unroll
      for (int r = 0; r < 16; ++r) {
        const int krow = (r & 3) + 8*(r >> 2) + 4*hi;
        if (kv0 + krow      > qg) st0[r] = -1e30f;
        if (kv0 + 32 + krow > qg) st1[r] = -1e30f;
      }
    }

    // ---- online softmax with defer-max (THR=8, log2 domain) ----
    float mx[8];
#pragma unroll
    for (int j = 0; j < 8; ++j)
      mx[j] = fmaxf(fmaxf(st0[2*j], st0[2*j+1]), fmaxf(st1[2*j], st1[2*j+1]));
    mx[0] = fmaxf(mx[0], mx[4]); mx[1] = fmaxf(mx[1], mx[5]);
    mx[2] = fmaxf(mx[2], mx[6]); mx[3] = fmaxf(mx[3], mx[7]);
    float mt = fmaxf(fmaxf(mx[0], mx[1]), fmaxf(mx[2], mx[3]));
    mt = xmax32(mt);
    if (!__all((int)(mt - mrun <= 8.0f))) {
      const float mnew = fmaxf(mrun, mt);
      const float fr = exp2f(mrun - mnew);
      mrun = mnew;
      lsum *= fr;
#pragma unroll
      for (int r = 0; r < 16; ++r) { acc0[r] *= fr; acc1[r] *= fr; }
    }
    float ps[8];
#pragma unroll
    for (int j = 0; j < 8; ++j) {
      st0[2*j]   = exp2f(st0[2*j]   - mrun);
      st0[2*j+1] = exp2f(st0[2*j+1] - mrun);
      st1[2*j]   = exp2f(st1[2*j]   - mrun);
      st1[2*j+1] = exp2f(st1[2*j+1] - mrun);
      ps[j] = (st0[2*j] + st0[2*j+1]) + (st1[2*j] + st1[2*j+1]);
    }
    ps[0] += ps[4]; ps[1] += ps[5]; ps[2] += ps[6]; ps[3] += ps[7];
    lsum += (ps[0] + ps[1]) + (ps[2] + ps[3]);

    // ---- P -> per-wave LDS Pw[q][key] (b64 writes), then B-fragments ----
#pragma unroll
    for (int r = 0; r < 16; r += 4) {
      const int k0i = (r >> 2)*8 + 4*hi;
      uint2 a0, a1;
      a0.x = pk2(st0[r],   st0[r+1]);  a0.y = pk2(st0[r+2], st0[r+3]);
      a1.x = pk2(st1[r],   st1[r+1]);  a1.y = pk2(st1[r+2], st1[r+3]);
      *(uint2*)&Pw[ql*PS_ + k0i]      = a0;
      *(uint2*)&Pw[ql*PS_ + 32 + k0i] = a1;
    }
    uint4 pb[4];
#pragma unroll
    for (int kc = 0; kc < 4; ++kc)
      pb[kc] = *(const uint4*)&Pw[ql*PS_ + kc*16 + hi*8];

    // ---- PV: accT[d][q] += V_frag x P_frag ----
    __builtin_amdgcn_s_setprio(1);
#pragma unroll
    for (int kc = 0; kc < 4; ++kc) {
      acc0 = mfma32(vf0[kc], pb[kc], acc0);
      acc1 = mfma32(vf1[kc], pb[kc], acc1);
    }
    __builtin_amdgcn_s_setprio(0);
  }

  // ---- epilogue: normalize, per-wave LDS transpose, coalesced store ----
  const float inv = 1.0f / xsum32(lsum);
#pragma unroll
  for (int r = 0; r < 16; ++r) {
    const int d0 = (r & 3) + 8*(r >> 2) + 4*hi;
    Pw[ql*PS_ + ( d0       ^ (8*(ql & 7)))] = f2bf(acc0[r] * inv);
    Pw[ql*PS_ + ((32 + d0) ^ (8*(ql & 7)))] = f2bf(acc1[r] * inv);
  }
  // read back rows (wave-internal; compiler inserts lgkmcnt), vector-store
  const int q1 = l >> 1, half = l & 1;
  const unsigned short* Er = Pw + q1*PS_;
  const int b = bh >> 4, h = bh & 15;
  unsigned short* outp = ctx + ((size_t)(b*S_ + q0 + w*32 + q1))*D_ + h*C_;
#pragma unroll
  for (int j = 0; j < 4; ++j) {
    const int clog = half*4 + j;
    const int cx = clog ^ (q1 & 7);
    uint4 val = *(const uint4*)&Er[cx*8];
    *(uint4*)(outp + clog*8) = val;
  }
}

// ---------------- launch ---------------------------------------------
extern "C" void kernel_launch(void* const* d_in, const int* in_sizes, int n_in,
                              void* d_out, int out_size, void* d_ws, size_t ws_size,
                              hipStream_t stream) {
  const float* x    = (const float*)d_in[0];
  const float* Wqkv = (const float*)d_in[1];
  const float* bqkv = (const float*)d_in[2];
  const float* Wout = (const float*)d_in[3];
  const float* bout = (const float*)d_in[4];
  float* out = (float*)d_out;

  unsigned short* ws = (unsigned short*)d_ws;
  unsigned short* xb    = ws;
  unsigned short* wqkvb = xb    + (size_t)M_ * D_;
  unsigned short* woutb = wqkvb + (size_t)N1_ * D_;
  unsigned short* Qb    = woutb + (size_t)D_ * D_;
  unsigned short* Kb    = Qb    + (size_t)B_*H_*S_*C_;
  unsigned short* Vtb   = Kb    + (size_t)B_*H_*S_*C_;
  unsigned short* ctxb  = Vtb   + (size_t)B_*H_*S_*C_;

  {
    const int ntot = N8X + N8W + N8O;
    cast_all<<<dim3((ntot+255)/256), dim3(256), 0, stream>>>(
        x, xb, Wqkv, wqkvb, Wout, woutb);
  }

  gemm_bt<1><<<dim3(N1_/128, M_/128), dim3(256), 0, stream>>>(
      xb, wqkvb, bqkv, nullptr, Qb, Kb, Vtb, N1_, D_);

  attn_fwd<<<dim3(32, 16), dim3(256), 0, stream>>>(Qb, Kb, Vtb, ctxb);

  gemm_bt<0><<<dim3(D_/128, M_/128), dim3(256), 0, stream>>>(
      ctxb, woutb, bout, out, nullptr, nullptr, nullptr, D_, D_);
}